// Round 4
// baseline (130.154 us; speedup 1.0000x reference)
//
#include <hip/hip_runtime.h>
#include <hip/hip_fp16.h>
#include <cstdint>
#include <cstddef>

#define IDIM 192
#define NSAMP 128
#define NRAYS 16384
#define NVOX (IDIM * IDIM * IDIM)   // 7077888

// z-pair fused table entry: lo = {gsum(v), opac(v)}, hi = {gsum(v+1), opac(v+1)}
typedef struct __align__(8) { __half2 lo; __half2 hi; } PairT;

__device__ __forceinline__ uint32_t rotl32(uint32_t x, int r) {
    return (x << r) | (x >> (32 - r));
}

// JAX threefry2x32, key (0,1), partitionable path: bits(i) = x0 ^ x1 of TF((0,1),(0,i))
__device__ __forceinline__ uint32_t threefry_bits(uint32_t i) {
    const uint32_t ks0 = 0u;
    const uint32_t ks1 = 1u;
    const uint32_t ks2 = 0x1BD11BDAu ^ ks0 ^ ks1;  // 0x1BD11BDB
    uint32_t x0 = 0u + ks0;
    uint32_t x1 = i + ks1;
#define TF_ROUND(r) { x0 += x1; x1 = rotl32(x1, (r)); x1 ^= x0; }
    TF_ROUND(13) TF_ROUND(15) TF_ROUND(26) TF_ROUND(6)
    x0 += ks1; x1 += ks2 + 1u;
    TF_ROUND(17) TF_ROUND(29) TF_ROUND(16) TF_ROUND(24)
    x0 += ks2; x1 += ks0 + 2u;
    TF_ROUND(13) TF_ROUND(15) TF_ROUND(26) TF_ROUND(6)
    x0 += ks0; x1 += ks1 + 3u;
    TF_ROUND(17) TF_ROUND(29) TF_ROUND(16) TF_ROUND(24)
    x0 += ks1; x1 += ks2 + 4u;
    TF_ROUND(13) TF_ROUND(15) TF_ROUND(26) TF_ROUND(6)
    x0 += ks2; x1 += ks0 + 5u;
#undef TF_ROUND
    return x0 ^ x1;
}

__global__ __launch_bounds__(256)
void fuse_kernel(const float* __restrict__ grid, const float* __restrict__ opacity,
                 PairT* __restrict__ tabp) {
    __shared__ float sh[256 * 9];
    __shared__ float sg[257];
    __shared__ float so[257];
    const int t = threadIdx.x;
    const int base = blockIdx.x * 256;
    const float* gp = grid + (size_t)base * 9;
    #pragma unroll
    for (int i = 0; i < 9; ++i) {
        sh[i * 256 + t] = gp[i * 256 + t];
    }
    __syncthreads();
    float s = 0.f;
    #pragma unroll
    for (int c = 0; c < 9; ++c) s += sh[t * 9 + c];
    sg[t] = s;
    so[t] = opacity[base + t];
    if (t == 0) {
        const int vn = (base + 256 < NVOX) ? base + 256 : NVOX - 1;
        const float* gn = grid + (size_t)vn * 9;
        float sn = 0.f;
        #pragma unroll
        for (int c = 0; c < 9; ++c) sn += gn[c];
        sg[256] = sn;
        so[256] = opacity[vn];
    }
    __syncthreads();
    PairT p;
    p.lo = __floats2half2_rn(sg[t], so[t]);
    p.hi = __floats2half2_rn(sg[t + 1], so[t + 1]);
    tabp[base + t] = p;
}

__global__ __launch_bounds__(NSAMP)
void rf_kernel(const float* __restrict__ x, const float* __restrict__ d,
               const PairT* __restrict__ tabp, float* __restrict__ out) {
    const int r = blockIdx.x;
    const int s = threadIdx.x;

    __shared__ float sv[NSAMP];   // unsorted samples
    __shared__ float st[NSAMP];   // sorted samples
    __shared__ float wtot[2];
    __shared__ float wsum[2];

    // --- ray setup (broadcast loads) ---
    const float ox = x[r * 3 + 0], oy = x[r * 3 + 1], oz = x[r * 3 + 2];
    const float dx = d[r * 3 + 0], dy = d[r * 3 + 1], dz = d[r * 3 + 2];
    const float inv_dx = 1.f / dx, inv_dy = 1.f / dy, inv_dz = 1.f / dz;
    const float INF = 7077888.f;  // 192^3
    const float BMAX = (float)(IDIM - 1);

    float tmin = -INF, tmax = INF;
    {
        float t0 = (0.f - ox) * inv_dx, t1 = (BMAX - ox) * inv_dx;
        tmin = fmaxf(tmin, fminf(t0, t1)); tmax = fminf(tmax, fmaxf(t0, t1));
        t0 = (0.f - oy) * inv_dy; t1 = (BMAX - oy) * inv_dy;
        tmin = fmaxf(tmin, fminf(t0, t1)); tmax = fminf(tmax, fmaxf(t0, t1));
        t0 = (0.f - oz) * inv_dz; t1 = (BMAX - oz) * inv_dz;
        tmin = fmaxf(tmin, fminf(t0, t1)); tmax = fminf(tmax, fmaxf(t0, t1));
    }

    // --- JAX-exact uniform sample (partitionable threefry) ---
    const uint32_t i = (uint32_t)(r * NSAMP + s);
    const uint32_t bits = threefry_bits(i);
    float u = __uint_as_float((bits >> 9) | 0x3f800000u) - 1.0f;
    u = fmaxf(0.f, u);
    const float vi = tmin + u * (tmax - tmin);
    sv[s] = vi;
    __syncthreads();

    // --- rank sort: rank = #{j: v_j < v_i} + #{j<i: v_j == v_i} ---
    int rank = 0;
    #pragma unroll 4
    for (int j = 0; j < NSAMP; j += 4) {
        const float4 q = *reinterpret_cast<const float4*>(&sv[j]);
        rank += (q.x < vi) | ((q.x == vi) & (j + 0 < s));
        rank += (q.y < vi) | ((q.y == vi) & (j + 1 < s));
        rank += (q.z < vi) | ((q.z == vi) & (j + 2 < s));
        rank += (q.w < vi) | ((q.w == vi) & (j + 3 < s));
    }
    st[rank] = vi;
    __syncthreads();
    const float ts = st[s];
    const float tn = (s < NSAMP - 1) ? st[s + 1] : ts;

    // --- trilinear interpolation from z-pair table: 4 gathers of 8B ---
    float opv = 0.f, hsv = 0.f;
    if (s < NSAMP - 1) {
        const float px = ox + ts * dx;
        const float py = oy + ts * dy;
        const float pz = oz + ts * dz;
        int ix = (int)floorf(px); ix = ix < 0 ? 0 : (ix > IDIM - 2 ? IDIM - 2 : ix);
        int iy = (int)floorf(py); iy = iy < 0 ? 0 : (iy > IDIM - 2 ? IDIM - 2 : iy);
        int iz = (int)floorf(pz); iz = iz < 0 ? 0 : (iz > IDIM - 2 ? IDIM - 2 : iz);
        const float fx = px - (float)ix;
        const float fy = py - (float)iy;
        const float fz = pz - (float)iz;
        const int SX = IDIM * IDIM, SY = IDIM;
        const int v000 = (ix * IDIM + iy) * IDIM + iz;

        const PairT c00 = tabp[v000];            // (x0,y0,z0/z1)
        const PairT c01 = tabp[v000 + SY];       // (x0,y1,z0/z1)
        const PairT c10 = tabp[v000 + SX];       // (x1,y0,z0/z1)
        const PairT c11 = tabp[v000 + SX + SY];  // (x1,y1,z0/z1)

        const float wz0 = 1.f - fz, wz1 = fz;
        const float2 a00 = __half22float2(c00.lo), b00 = __half22float2(c00.hi);
        const float2 a01 = __half22float2(c01.lo), b01 = __half22float2(c01.hi);
        const float2 a10 = __half22float2(c10.lo), b10 = __half22float2(c10.hi);
        const float2 a11 = __half22float2(c11.lo), b11 = __half22float2(c11.hi);
        // z-lerp each corner pair
        const float g00 = wz0 * a00.x + wz1 * b00.x, o00 = wz0 * a00.y + wz1 * b00.y;
        const float g01 = wz0 * a01.x + wz1 * b01.x, o01 = wz0 * a01.y + wz1 * b01.y;
        const float g10 = wz0 * a10.x + wz1 * b10.x, o10 = wz0 * a10.y + wz1 * b10.y;
        const float g11 = wz0 * a11.x + wz1 * b11.x, o11 = wz0 * a11.y + wz1 * b11.y;
        // y-lerp then x-lerp
        const float wy0 = 1.f - fy, wy1 = fy;
        const float g0 = wy0 * g00 + wy1 * g01, o0 = wy0 * o00 + wy1 * o01;
        const float g1 = wy0 * g10 + wy1 * g11, o1 = wy0 * o10 + wy1 * o11;
        const float wx0 = 1.f - fx, wx1 = fx;
        hsv = wx0 * g0 + wx1 * g1;
        opv = wx0 * o0 + wx1 * o1;
    }

    // --- compositing: exclusive prefix sum of cur over 127 entries ---
    const float cur = (s < NSAMP - 1) ? (tn - ts) * opv : 0.f;
    float incl = cur;
    #pragma unroll
    for (int off = 1; off < 64; off <<= 1) {
        const float v2 = __shfl_up(incl, off, 64);
        if ((s & 63) >= off) incl += v2;
    }
    if ((s & 63) == 63) wtot[s >> 6] = incl;
    __syncthreads();
    if (s >= 64) incl += wtot[0];
    const float excl = incl - cur;

    float contrib = 0.f;
    if (s < NSAMP - 1) {
        const float color = 1.f / (1.f + __expf(-hsv));
        contrib = __expf(-excl) * (1.f - __expf(-cur)) * color;
    }

    // --- block reduction ---
    #pragma unroll
    for (int off = 32; off > 0; off >>= 1) contrib += __shfl_down(contrib, off, 64);
    if ((s & 63) == 0) wsum[s >> 6] = contrib;
    __syncthreads();
    if (s == 0) out[r] = wsum[0] + wsum[1];
}

extern "C" void kernel_launch(void* const* d_in, const int* in_sizes, int n_in,
                              void* d_out, int out_size, void* d_ws, size_t ws_size,
                              hipStream_t stream) {
    const float* x       = (const float*)d_in[0];
    const float* d       = (const float*)d_in[1];
    const float* grid    = (const float*)d_in[2];
    const float* opacity = (const float*)d_in[3];
    float* out = (float*)d_out;

    fuse_kernel<<<NVOX / 256, 256, 0, stream>>>(grid, opacity, (PairT*)d_ws);
    rf_kernel<<<NRAYS, NSAMP, 0, stream>>>(x, d, (const PairT*)d_ws, out);
}